// Round 14
// baseline (101.144 us; speedup 1.0000x reference)
//
#include <hip/hip_runtime.h>
#include <hip/hip_cooperative_groups.h>
#include <float.h>
#include <math.h>

namespace cg = cooperative_groups;

#define B_NUM 64
#define P_NUM 8732
#define T_NUM 16
#define C_NUM 81
#define TPB   512
#define RPB_LSE 128                             // rows per negce unit (8 waves x 16)
#define NUNITS ((B_NUM * P_NUM) / RPB_LSE)      // 4366
#define GRID1 (B_NUM + NUNITS)                  // fallback k_fused1 grid
#define GRID_C 256                              // cooperative grid (1 block/CU)
#define PLMAX 32
#define NQ4 2183                                // 8732/4 float4s per batch

__device__ __forceinline__ float smooth_l1(float d) {
    float ad = fabsf(d);
    return (ad < 1.0f) ? 0.5f * d * d : ad - 0.5f;
}

struct MatchSh {
    float s_t[T_NUM][4];
    int   s_lab[T_NUM];
    unsigned short s_m[P_NUM];   // bit15 = positive flag, low bits = truth idx
    float s_rv[16 * T_NUM];
    int   s_ri[16 * T_NUM];
    int   s_bp[T_NUM];
    float s_red[16];
    int   s_redi[16];
    int   s_plist[PLMAX];
    int   s_pcount;
};
struct SelSh {
    int   s_wh[16][256];         // wave-private histograms
    int   s_hist[256];
    unsigned int s_bm[273];
    int   s_sel, s_rem, s_last;
    float s_sv[16]; int s_sc[16]; float s_pv[16];
    unsigned int s_mn[16], s_mx[16]; int s_nz[16];
    int   s_p1skip, s_p1sel, s_p1rem;
};
union __align__(16) Sh { MatchSh m; SelSh s; };

// ---------------------------------------------------------------------------
// negce unit: 128 rows, 8 waves x 4 groups x 16 lanes; 4 rows = 81 aligned f4.
// ---------------------------------------------------------------------------
__device__ __forceinline__ void negce_unit(
    const float* __restrict__ conf, float* __restrict__ negce,
    int u, int wv, int lane)
{
    const int g  = lane >> 4;
    const int lg = lane & 15;
    const int gr0 = u * RPB_LSE + wv * 16 + g * 4;
    const float4* g4 = (const float4*)(conf) + (size_t)gr0 * 81 / 4;

    float4 q0 = g4[lg];
    float4 q1 = g4[lg + 16];
    float4 q2 = g4[lg + 32];
    float4 q3 = g4[lg + 48];
    float4 q4 = g4[lg + 64];
    float4 q5 = make_float4(0.f, 0.f, 0.f, 0.f);
    if (lg == 0) q5 = g4[80];

    float x0 = 0.0f;
    if (lg == 0)  x0 = q0.x;    // pos 0   -> row 0
    if (lg == 4)  x0 = q1.y;    // pos 81  -> row 1
    if (lg == 8)  x0 = q2.z;    // pos 162 -> row 2
    if (lg == 12) x0 = q3.w;    // pos 243 -> row 3

    float a0 = 0.f, a1 = 0.f, a2 = 0.f, a3 = 0.f;
    a0 += __expf(q0.x) + __expf(q0.y) + __expf(q0.z) + __expf(q0.w);
    {
        int p = 64 + 4 * lg; float e;
        e = __expf(q1.x); if (p + 0 >= 81) a1 += e; else a0 += e;
        e = __expf(q1.y); if (p + 1 >= 81) a1 += e; else a0 += e;
        e = __expf(q1.z); if (p + 2 >= 81) a1 += e; else a0 += e;
        e = __expf(q1.w); if (p + 3 >= 81) a1 += e; else a0 += e;
    }
    {
        int p = 128 + 4 * lg; float e;
        e = __expf(q2.x); if (p + 0 >= 162) a2 += e; else a1 += e;
        e = __expf(q2.y); if (p + 1 >= 162) a2 += e; else a1 += e;
        e = __expf(q2.z); if (p + 2 >= 162) a2 += e; else a1 += e;
        e = __expf(q2.w); if (p + 3 >= 162) a2 += e; else a1 += e;
    }
    {
        int p = 192 + 4 * lg; float e;
        e = __expf(q3.x); if (p + 0 >= 243) a3 += e; else a2 += e;
        e = __expf(q3.y); if (p + 1 >= 243) a3 += e; else a2 += e;
        e = __expf(q3.z); if (p + 2 >= 243) a3 += e; else a2 += e;
        e = __expf(q3.w); if (p + 3 >= 243) a3 += e; else a2 += e;
    }
    a3 += __expf(q4.x) + __expf(q4.y) + __expf(q4.z) + __expf(q4.w);
    if (lg == 0)
        a3 += __expf(q5.x) + __expf(q5.y) + __expf(q5.z) + __expf(q5.w);

#pragma unroll
    for (int m = 1; m < 16; m <<= 1) {
        a0 += __shfl_xor(a0, m);
        a1 += __shfl_xor(a1, m);
        a2 += __shfl_xor(a2, m);
        a3 += __shfl_xor(a3, m);
    }
    if ((lg & 3) == 0) {
        int sel = lg >> 2;
        float s = (sel == 0) ? a0 : (sel == 1) ? a1 : (sel == 2) ? a2 : a3;
        negce[gr0 + sel] = __logf(s) - x0;
    }
}

// ---------------------------------------------------------------------------
// match phase (512 threads): num_pos, loc loss, positive list.
// ---------------------------------------------------------------------------
__device__ __forceinline__ void match_phase(
    MatchSh& shm, int b,
    const float* __restrict__ loc, const float* __restrict__ priors,
    const float* __restrict__ truths, const int* __restrict__ labels,
    int* __restrict__ num_pos, float* __restrict__ loss_l_b,
    int* __restrict__ plist_g, bool write_plist,
    int& np_out, int& myplist_out)
{
    const int tid = threadIdx.x;
    const int lane = tid & 63, wv = tid >> 6;

    if (tid == 0) shm.s_pcount = 0;
    if (tid < T_NUM * 4) ((float*)shm.s_t)[tid] = truths[b * T_NUM * 4 + tid];
    if (tid < T_NUM)     shm.s_lab[tid] = labels[b * T_NUM + tid];
    __syncthreads();

    float bpv[T_NUM]; int bpi[T_NUM];
#pragma unroll
    for (int t = 0; t < T_NUM; ++t) { bpv[t] = -1.0f; bpi[t] = 0; }

    const float4* pr4 = (const float4*)priors;
    for (int p = tid; p < P_NUM; p += TPB) {
        float4 pr = pr4[p];
        float px0 = pr.x - 0.5f * pr.z, py0 = pr.y - 0.5f * pr.w;
        float px1 = pr.x + 0.5f * pr.z, py1 = pr.y + 0.5f * pr.w;
        float btv = -1.0f; int bti = 0;
#pragma unroll
        for (int t = 0; t < T_NUM; ++t) {
            float ix = fminf(shm.s_t[t][2], px1) - fmaxf(shm.s_t[t][0], px0);
            float iy = fminf(shm.s_t[t][3], py1) - fmaxf(shm.s_t[t][1], py0);
            ix = fmaxf(ix, 0.0f); iy = fmaxf(iy, 0.0f);
            float ov = ix * iy;
            if (ov > btv) { btv = ov; bti = t; }          // first max over t
            if (ov > bpv[t]) { bpv[t] = ov; bpi[t] = p; } // first max over p
        }
        shm.s_m[p] = (unsigned short)((btv >= 0.5f ? 0x8000 : 0) | bti);
    }
    __syncthreads();

#pragma unroll
    for (int t = 0; t < T_NUM; ++t) {
        float v = bpv[t]; int i = bpi[t];
#pragma unroll
        for (int off = 32; off > 0; off >>= 1) {
            float ov = __shfl_down(v, off);
            int   oi = __shfl_down(i, off);
            if (ov > v || (ov == v && oi < i)) { v = ov; i = oi; }
        }
        if (lane == 0) { shm.s_rv[wv * T_NUM + t] = v; shm.s_ri[wv * T_NUM + t] = i; }
    }
    __syncthreads();
    if (tid < T_NUM) {
        float v = shm.s_rv[tid]; int i = shm.s_ri[tid];
        for (int w = 1; w < TPB / 64; ++w) {
            float ov = shm.s_rv[w * T_NUM + tid]; int oi = shm.s_ri[w * T_NUM + tid];
            if (ov > v || (ov == v && oi < i)) { v = ov; i = oi; }
        }
        shm.s_bp[tid] = i;
    }
    __syncthreads();
    if (tid == 0) {
        for (int t = 0; t < T_NUM; ++t)
            shm.s_m[shm.s_bp[t]] = (unsigned short)(0x8000 | t);
    }
    __syncthreads();

    int cnt = 0; float lsum = 0.0f;
    const float4* loc4 = (const float4*)loc;
    for (int p = tid; p < P_NUM; p += TPB) {
        unsigned short mm = shm.s_m[p];
        if (mm & 0x8000) {
            int ti = mm & 0x7FFF;
            int c = shm.s_lab[ti] + 1;
            cnt++;
            int sl = atomicAdd(&shm.s_pcount, 1);
            if (sl < PLMAX) shm.s_plist[sl] = (p << 8) | c;
            float4 pr = pr4[p];
            float mx0 = shm.s_t[ti][0], my0 = shm.s_t[ti][1];
            float mx1 = shm.s_t[ti][2], my1 = shm.s_t[ti][3];
            float gx = ((mx0 + mx1) * 0.5f - pr.x) / (0.1f * pr.z);
            float gy = ((my0 + my1) * 0.5f - pr.y) / (0.1f * pr.w);
            float gw = __logf((mx1 - mx0) / pr.z + 1e-10f) / 0.2f;
            float gh = __logf((my1 - my0) / pr.w + 1e-10f) / 0.2f;
            float4 l = loc4[(size_t)b * P_NUM + p];
            lsum += smooth_l1(l.x - gx) + smooth_l1(l.y - gy)
                  + smooth_l1(l.z - gw) + smooth_l1(l.w - gh);
        }
    }
#pragma unroll
    for (int off = 32; off > 0; off >>= 1) {
        lsum += __shfl_down(lsum, off);
        cnt  += __shfl_down(cnt, off);
    }
    if (lane == 0) { shm.s_red[wv] = lsum; shm.s_redi[wv] = cnt; }
    __syncthreads();
    if (tid == 0) {
        float L = 0.0f; int C2 = 0;
        for (int w = 0; w < TPB / 64; ++w) { L += shm.s_red[w]; C2 += shm.s_redi[w]; }
        num_pos[b] = C2;
        loss_l_b[b] = L;
    }
    __syncthreads();
    np_out = shm.s_pcount;
    myplist_out = (tid < np_out && tid < PLMAX) ? shm.s_plist[tid] : -1;
    if (write_plist && tid < np_out && tid < PLMAX)
        plist_g[b * PLMAX + tid] = shm.s_plist[tid];
}

// ---------------------------------------------------------------------------
// select phase (templated on block size): radix-select top-nn sum over negce
// (pass-1 analytic shortcut) + positive CE + completion + final reduce.
// ---------------------------------------------------------------------------
template<int NT>
__device__ __forceinline__ void select_batch(
    SelSh& ss, int b, int np, int myplist,
    const float* __restrict__ negce, const float* __restrict__ conf,
    const int* __restrict__ num_pos, const float* __restrict__ loss_l_b,
    float* __restrict__ negsum_b, float* __restrict__ pce_b,
    int* __restrict__ sel_ctr, float* __restrict__ out)
{
    constexpr int NW = NT / 64;
    constexpr int NF4 = (NQ4 + NT - 1) / NT;
    constexpr int VE = NF4 * 4;
    const int tid = threadIdx.x, lane = tid & 63, wv = tid >> 6;

    if (tid < 273) ss.s_bm[tid] = 0u;
    if (tid == 0) ss.s_p1skip = 0;
    __syncthreads();
    float pce = 0.0f;
    if (myplist >= 0) {
        int p = myplist >> 8, c = myplist & 255;
        size_t idx = (size_t)b * P_NUM + p;
        size_t ci = idx * C_NUM;
        pce = negce[idx] + conf[ci] - conf[ci + c];
        atomicOr(&ss.s_bm[p >> 5], 1u << (p & 31));
    }
    __syncthreads();

    unsigned int val[VE];
    const float4* nb4 = (const float4*)(negce + (size_t)b * P_NUM);
#pragma unroll
    for (int i = 0; i < NF4; ++i) {
        int q = tid + i * NT;
        float4 v4 = make_float4(0.f, 0.f, 0.f, 0.f);
        if (q < NQ4) v4 = nb4[q];
        float vv[4] = {v4.x, v4.y, v4.z, v4.w};
#pragma unroll
        for (int k = 0; k < 4; ++k) {
            int p = 4 * q + k;
            unsigned int u = 0u;
            if (q < NQ4 && !((ss.s_bm[p >> 5] >> (p & 31)) & 1u))
                u = __float_as_uint(fmaxf(vv[k], 0.0f));
            val[i * 4 + k] = u;
        }
    }

    int nn = 3 * np; if (nn > P_NUM - 1) nn = P_NUM - 1;

    // pass-1 shortcut: top-byte min/max over nonzero + count
    {
        unsigned int tmn = 255u, tmx = 0u; int nz = 0;
#pragma unroll
        for (int i = 0; i < VE; ++i) {
            unsigned int v = val[i];
            if (v) {
                unsigned int t = v >> 24;
                tmn = (t < tmn) ? t : tmn;
                tmx = (t > tmx) ? t : tmx;
                nz++;
            }
        }
#pragma unroll
        for (int off = 32; off > 0; off >>= 1) {
            unsigned int omn = __shfl_down(tmn, off);
            unsigned int omx = __shfl_down(tmx, off);
            int onz = __shfl_down(nz, off);
            tmn = (omn < tmn) ? omn : tmn;
            tmx = (omx > tmx) ? omx : tmx;
            nz += onz;
        }
        if (lane == 0) { ss.s_mn[wv] = tmn; ss.s_mx[wv] = tmx; ss.s_nz[wv] = nz; }
        __syncthreads();
        if (tid == 0) {
            unsigned int MN = 255u, MX = 0u; int NZ = 0;
            for (int w = 0; w < NW; ++w) {
                if (ss.s_mn[w] < MN) MN = ss.s_mn[w];
                if (ss.s_mx[w] > MX) MX = ss.s_mx[w];
                NZ += ss.s_nz[w];
            }
            if (MN == MX && NZ > 0) {
                ss.s_p1skip = 1;
                if (nn <= NZ) { ss.s_p1sel = (int)MX; ss.s_p1rem = nn; }
                else          { ss.s_p1sel = 0;       ss.s_p1rem = nn - NZ; }
            }
        }
        __syncthreads();
    }

    if (nn > 0) {
        unsigned int prefix = 0;
        int k = nn;
        const int shifts[4] = {24, 16, 8, 0};
        for (int si = 0; si < 4; ++si) {
            const int shift = shifts[si];
            if (si == 0 && ss.s_p1skip) {
                prefix = ((unsigned int)ss.s_p1sel) << 24;
                k = ss.s_p1rem;
                continue;
            }
            for (int i = tid; i < NW * 256; i += NT) ((int*)ss.s_wh)[i] = 0;
            __syncthreads();
            const unsigned int pmask = (shift == 24) ? 0u : (0xFFFFFFFFu << (shift + 8));
#pragma unroll
            for (int i = 0; i < VE; ++i) {
                unsigned int v = val[i];
                if ((v & pmask) == prefix)
                    atomicAdd(&ss.s_wh[wv][(v >> shift) & 0xFF], 1);
            }
            __syncthreads();
            if (tid < 256) {
                int s = 0;
                for (int w = 0; w < NW; ++w) s += ss.s_wh[w][tid];
                ss.s_hist[tid] = s;
            }
            __syncthreads();
            if (wv == 0) {
                int c0 = ss.s_hist[4 * lane + 0], c1 = ss.s_hist[4 * lane + 1];
                int c2 = ss.s_hist[4 * lane + 2], c3 = ss.s_hist[4 * lane + 3];
                int t3 = c3, t2 = c2 + t3, t1 = c1 + t2, t0 = c0 + t1;
                int g = t0, G = g;
#pragma unroll
                for (int off = 1; off < 64; off <<= 1) {
                    int o = __shfl_down(G, off);
                    if (lane + off < 64) G += o;
                }
                int above = G - g;
                int suf0 = t0 + above, suf1 = t1 + above;
                int suf2 = t2 + above, suf3 = t3 + above, suf4 = above;
                if (suf0 >= k && suf1 < k) { ss.s_sel = 4 * lane + 0; ss.s_rem = k - suf1; }
                if (suf1 >= k && suf2 < k) { ss.s_sel = 4 * lane + 1; ss.s_rem = k - suf2; }
                if (suf2 >= k && suf3 < k) { ss.s_sel = 4 * lane + 2; ss.s_rem = k - suf3; }
                if (suf3 >= k && suf4 < k) { ss.s_sel = 4 * lane + 3; ss.s_rem = k - suf4; }
            }
            __syncthreads();
            prefix |= ((unsigned int)ss.s_sel) << shift;
            k = ss.s_rem;
        }

        float sgt = 0.0f; int cgt = 0;
#pragma unroll
        for (int i = 0; i < VE; ++i) {
            unsigned int v = val[i];
            if (v > prefix) { sgt += __uint_as_float(v); cgt++; }
        }
#pragma unroll
        for (int off = 32; off > 0; off >>= 1) {
            sgt += __shfl_down(sgt, off);
            cgt += __shfl_down(cgt, off);
        }
        if (lane == 0) { ss.s_sv[wv] = sgt; ss.s_sc[wv] = cgt; }
        __syncthreads();
        if (tid == 0) {
            float S = 0.0f; int Ct = 0;
            for (int w = 0; w < NW; ++w) { S += ss.s_sv[w]; Ct += ss.s_sc[w]; }
            negsum_b[b] = S + (float)(nn - Ct) * __uint_as_float(prefix);
        }
    } else {
        if (tid == 0) negsum_b[b] = 0.0f;
    }

#pragma unroll
    for (int off = 32; off > 0; off >>= 1) pce += __shfl_down(pce, off);
    if (lane == 0) ss.s_pv[wv] = pce;
    __syncthreads();
    if (tid == 0) {
        float PCE = 0.0f;
        for (int w = 0; w < NW; ++w) PCE += ss.s_pv[w];
        pce_b[b] = PCE;
    }

    if (tid == 0) {
        __threadfence();
        int old = atomicAdd(sel_ctr, 1);
        ss.s_last = (old == B_NUM - 1) ? 1 : 0;
    }
    __syncthreads();
    if (ss.s_last && wv == 0) {
        __threadfence();
        float ll = loss_l_b[lane];
        float ns = negsum_b[lane];
        float pc = pce_b[lane];
        int   npg = num_pos[lane];
#pragma unroll
        for (int off = 32; off > 0; off >>= 1) {
            ll += __shfl_down(ll, off);
            ns += __shfl_down(ns, off);
            pc += __shfl_down(pc, off);
            npg += __shfl_down(npg, off);
        }
        if (lane == 0) {
            float N = (float)(npg > 1 ? npg : 1);
            out[0] = ll / N;
            out[1] = (pc + ns) / N;
        }
    }
}

// ---------------------------------------------------------------------------
// Cooperative single kernel: 256 blocks (1/CU). Blocks [0,64) match+select,
// blocks [64,256) stream negce units; one grid sync between phases.
// ---------------------------------------------------------------------------
__global__ __launch_bounds__(TPB) void k_coop(
    const float* __restrict__ loc, const float* __restrict__ conf,
    const float* __restrict__ priors, const float* __restrict__ truths,
    const int* __restrict__ labels,
    int* __restrict__ num_pos, float* __restrict__ loss_l_b,
    float* __restrict__ negsum_b, float* __restrict__ pce_b,
    float* __restrict__ negce, int* __restrict__ plist_g,
    int* __restrict__ sel_ctr, float* __restrict__ out)
{
    __shared__ Sh sh;
    const int blk = blockIdx.x;
    const int lane = threadIdx.x & 63, wv = threadIdx.x >> 6;

    int np_loc = 0, myplist = -1;
    if (blk < B_NUM) {
        match_phase(sh.m, blk, loc, priors, truths, labels,
                    num_pos, loss_l_b, plist_g, false, np_loc, myplist);
    } else {
        for (int u = blk - B_NUM; u < NUNITS; u += (GRID_C - B_NUM))
            negce_unit(conf, negce, u, wv, lane);
    }

    cg::this_grid().sync();

    if (blk < B_NUM)
        select_batch<TPB>(sh.s, blk, np_loc, myplist, negce, conf,
                          num_pos, loss_l_b, negsum_b, pce_b, sel_ctr, out);
}

// ---------------------------------------------------------------------------
// Fallback pair (proven round-12 structure).
// ---------------------------------------------------------------------------
__global__ __launch_bounds__(TPB, 4) void k_fused1(
    const float* __restrict__ loc, const float* __restrict__ conf,
    const float* __restrict__ priors, const float* __restrict__ truths,
    const int* __restrict__ labels,
    int* __restrict__ num_pos, float* __restrict__ loss_l_b,
    float* __restrict__ negce, int* __restrict__ plist_g,
    int* __restrict__ sel_ctr)
{
    __shared__ MatchSh shm;
    const int lane = threadIdx.x & 63, wv = threadIdx.x >> 6;

    if (blockIdx.x >= B_NUM) {
        negce_unit(conf, negce, blockIdx.x - B_NUM, wv, lane);
        return;
    }
    const int b = blockIdx.x;
    if (b == 0 && threadIdx.x == 0) *sel_ctr = 0;
    int np_loc, myplist;
    match_phase(shm, b, loc, priors, truths, labels,
                num_pos, loss_l_b, plist_g, true, np_loc, myplist);
}

__global__ __launch_bounds__(1024) void k_select(
    const float* __restrict__ negce, const float* __restrict__ conf,
    const int* __restrict__ plist_g, const int* __restrict__ num_pos,
    float* __restrict__ loss_l_b, float* __restrict__ negsum_b,
    float* __restrict__ pce_b, int* __restrict__ sel_ctr,
    float* __restrict__ out)
{
    __shared__ SelSh ss;
    const int b = blockIdx.x, tid = threadIdx.x;
    const int np = num_pos[b];
    int myplist = (tid < np && tid < PLMAX) ? plist_g[b * PLMAX + tid] : -1;
    select_batch<1024>(ss, b, np, myplist, negce, conf,
                       num_pos, loss_l_b, negsum_b, pce_b, sel_ctr, out);
}

// ---------------------------------------------------------------------------
extern "C" void kernel_launch(void* const* d_in, const int* in_sizes, int n_in,
                              void* d_out, int out_size, void* d_ws, size_t ws_size,
                              hipStream_t stream) {
    const float* loc    = (const float*)d_in[0];
    const float* conf   = (const float*)d_in[1];
    const float* priors = (const float*)d_in[2];
    const float* truths = (const float*)d_in[3];
    const int*   labels = (const int*)d_in[4];
    float* out = (float*)d_out;

    int*   ws_i = (int*)d_ws;
    float* ws_f = (float*)d_ws;
    int*   num_pos   = ws_i;                         // [0,64)
    float* loss_l_b  = ws_f + 64;                    // [64,128)
    float* negsum_b  = ws_f + 128;                   // [128,192)
    float* pce_b     = ws_f + 192;                   // [192,256)
    int*   sel_ctr   = ws_i + 256;                   // [256]
    int*   plist_g   = ws_i + 1024;                  // [1024, 1024+64*32)
    float* negce     = ws_f + 4096;                  // [4096, 4096+B*P)

    // zero sel_ctr (graph-capturable, stream-ordered); needed by coop path.
    hipMemsetAsync((void*)sel_ctr, 0, sizeof(int), stream);

    void* args[] = { (void*)&loc, (void*)&conf, (void*)&priors, (void*)&truths,
                     (void*)&labels, (void*)&num_pos, (void*)&loss_l_b,
                     (void*)&negsum_b, (void*)&pce_b, (void*)&negce,
                     (void*)&plist_g, (void*)&sel_ctr, (void*)&out };
    hipError_t e = hipLaunchCooperativeKernel((const void*)k_coop, dim3(GRID_C),
                                              dim3(TPB), args, 0, stream);
    if (e != hipSuccess) {
        // deterministic fallback: proven two-kernel path
        k_fused1<<<GRID1, TPB, 0, stream>>>(loc, conf, priors, truths, labels,
                                            num_pos, loss_l_b, negce, plist_g, sel_ctr);
        k_select<<<B_NUM, 1024, 0, stream>>>(negce, conf, plist_g, num_pos,
                                             loss_l_b, negsum_b, pce_b, sel_ctr, out);
    }
}